// Round 7
// baseline (419.379 us; speedup 1.0000x reference)
//
#include <hip/hip_runtime.h>
#include <cfloat>

typedef unsigned short u16;
typedef u16   u16x4 __attribute__((ext_vector_type(4)));
typedef float f32x4 __attribute__((ext_vector_type(4)));
typedef _Float16 f16x8 __attribute__((ext_vector_type(8)));

template <int N> struct ic { static constexpr int value = N; };

#define GL2LDS(gp, lp) __builtin_amdgcn_global_load_lds(                      \
    (const __attribute__((address_space(1))) void*)(gp),                      \
    (__attribute__((address_space(3))) void*)(lp), 16, 0, 0)

#define PIN16(x) asm volatile("" :: "v"(__builtin_bit_cast(f32x4, (x))))

__device__ __forceinline__ void f32_to_f16pair(float f, u16& hi, u16& lo) {
  _Float16 h = (_Float16)f;               // RNE
  _Float16 l = (_Float16)(f - (float)h);  // residual (exact subtraction)
  hi = __builtin_bit_cast(u16, h);
  lo = __builtin_bit_cast(u16, l);
}

// Pretile a [R,512] fp32 matrix into f16 hi/lo panels (exact LDS image,
// XOR-swizzled ((r&7)<<4)); optional row sum-of-squares + fp32 passthrough.
__global__ __launch_bounds__(128) void vq_prep(
    const float* __restrict__ src, u16* __restrict__ pan,
    float* __restrict__ sq, float* __restrict__ copy_out) {
  __shared__ float red[2];
  const int row_g = blockIdx.x;
  const int t = threadIdx.x;
  float4 v = reinterpret_cast<const float4*>(src + (size_t)row_g * 512)[t];
  if (copy_out)
    reinterpret_cast<float4*>(copy_out + (size_t)row_g * 512)[t] = v;
  u16 hi[4], lo[4];
  float f[4] = {v.x, v.y, v.z, v.w};
  #pragma unroll
  for (int i = 0; i < 4; ++i) f32_to_f16pair(f[i], hi[i], lo[i]);
  const int d = t * 4;
  const int tile = row_g >> 8, r = row_g & 255;
  const int s = d >> 5, c = d & 31;
  const size_t pbase = ((size_t)tile * 16 + s) * 32768;
  const unsigned swz = ((unsigned)(r & 7)) << 4;
  const unsigned bh = ((unsigned)(r * 128 + c * 2)) ^ swz;
  const unsigned bl = ((unsigned)(r * 128 + 64 + c * 2)) ^ swz;
  u16x4 th = {hi[0], hi[1], hi[2], hi[3]};
  u16x4 tl = {lo[0], lo[1], lo[2], lo[3]};
  *reinterpret_cast<u16x4*>((char*)pan + pbase + bh) = th;
  *reinterpret_cast<u16x4*>((char*)pan + pbase + bl) = tl;
  if (sq) {
    float ssum = v.x*v.x + v.y*v.y + v.z*v.z + v.w*v.w;
    #pragma unroll
    for (int m = 1; m < 64; m <<= 1) ssum += __shfl_xor(ssum, m);
    if ((t & 63) == 0) red[t >> 6] = ssum;
    __syncthreads();
    if (t == 0) sq[row_g] = red[0] + red[1];
  }
}

// ---------------- real GEMM (R5 structure, SIMD-mate antiphase fix) --------
template <int INLINE_A>
__global__ __launch_bounds__(512, 2) void vq_gemm(
    const float* __restrict__ X,
    const u16* __restrict__ Apan, const u16* __restrict__ Bpan,
    const float* __restrict__ c2,
    float2* __restrict__ part, int nnt) {
  __shared__ u16 sA0[16384], sA1[16384], sB0[16384], sB1[16384];
  const int tid = threadIdx.x;
  const int lane = tid & 63, wid = tid >> 6;
  const int wm = wid >> 2, wn = wid & 3;
  const int nwg = gridDim.x;
  const int bid = blockIdx.x;
  const int swb = (bid & 7) * (nwg >> 3) + (bid >> 3);
  const int mtile = swb / nnt, ntile = swb % nnt;
  const int lrow = lane & 15, kgrp = lane >> 4;
  f32x4 acc[8][4] = {};

  #define SCHED0 __builtin_amdgcn_sched_barrier(0)

  auto stageFullA = [&](u16* dst, int s) {
    const char* g = (const char*)Apan + ((size_t)mtile * 16 + s) * 32768;
    #pragma unroll
    for (int i = 0; i < 4; ++i) {
      const int off = i * 8192 + wid * 1024;
      GL2LDS(g + off + lane * 16, (char*)dst + off);
    }
  };
  auto stageFullB = [&](u16* dst, int s) {
    const char* g = (const char*)Bpan + ((size_t)ntile * 16 + s) * 32768;
    #pragma unroll
    for (int i = 0; i < 4; ++i) {
      const int off = i * 8192 + wid * 1024;
      GL2LDS(g + off + lane * 16, (char*)dst + off);
    }
  };
  auto inlineA = [&](u16* dst, int s) {
    const float* ga = X + ((size_t)mtile * 256) * 512 + s * 32;
    #pragma unroll
    for (int p = 0; p < 4; ++p) {
      const int cch = tid + p * 512;
      const int r = cch >> 3, c0 = (cch & 7) * 4;
      float4 v = *reinterpret_cast<const float4*>(ga + (size_t)r * 512 + c0);
      u16 hi[4], lo[4];
      float f[4] = {v.x, v.y, v.z, v.w};
      #pragma unroll
      for (int i2 = 0; i2 < 4; ++i2) f32_to_f16pair(f[i2], hi[i2], lo[i2]);
      const unsigned swz = ((unsigned)(r & 7)) << 4;
      const unsigned bh = ((unsigned)(r * 128 + c0 * 2)) ^ swz;
      const unsigned bl = ((unsigned)(r * 128 + 64 + c0 * 2)) ^ swz;
      u16x4 th = {hi[0], hi[1], hi[2], hi[3]};
      u16x4 tl = {lo[0], lo[1], lo[2], lo[3]};
      *reinterpret_cast<u16x4*>((char*)dst + bh) = th;
      *reinterpret_cast<u16x4*>((char*)dst + bl) = tl;
    }
  };

  auto readA = [&](const u16* buf, int rh, f16x8* h, f16x8* l) {
    #pragma unroll
    for (int t = 0; t < 4; ++t) {
      const int ar = rh * 128 + wm * 64 + t * 16 + lrow;
      const unsigned swz = ((unsigned)(ar & 7)) << 4;
      const unsigned a0 = (unsigned)(ar * 128 + kgrp * 16);
      h[t] = *reinterpret_cast<const f16x8*>((const char*)buf + (a0 ^ swz));
      l[t] = *reinterpret_cast<const f16x8*>((const char*)buf + ((a0 + 64) ^ swz));
    }
  };
  auto readB = [&](const u16* buf, int ch, f16x8* h, f16x8* l) {
    #pragma unroll
    for (int u = 0; u < 2; ++u) {
      const int br = ch * 128 + wn * 32 + u * 16 + lrow;
      const unsigned swz = ((unsigned)(br & 7)) << 4;
      const unsigned b0 = (unsigned)(br * 128 + kgrp * 16);
      h[u] = *reinterpret_cast<const f16x8*>((const char*)buf + (b0 ^ swz));
      l[u] = *reinterpret_cast<const f16x8*>((const char*)buf + ((b0 + 64) ^ swz));
    }
  };

  auto kloop = [&](auto PC) {
    constexpr int P = decltype(PC)::value;
    f16x8 Xh[4], Xl[4], Yh[4], Yl[4];
    f16x8 Uh[2], Ul[2], Vh[2], Vl[2];

    auto MF = [&](auto RH, auto CH, const f16x8* ah, const f16x8* al,
                  const f16x8* bh, const f16x8* bl) {
      constexpr int rh = decltype(RH)::value, ch = decltype(CH)::value;
      __builtin_amdgcn_s_setprio(1);
      #pragma unroll
      for (int t = 0; t < 4; ++t) {
        #pragma unroll
        for (int u = 0; u < 2; ++u) {
          acc[rh*4+t][ch*2+u] = __builtin_amdgcn_mfma_f32_16x16x32_f16(ah[t], bh[u], acc[rh*4+t][ch*2+u], 0, 0, 0);
          acc[rh*4+t][ch*2+u] = __builtin_amdgcn_mfma_f32_16x16x32_f16(ah[t], bl[u], acc[rh*4+t][ch*2+u], 0, 0, 0);
          acc[rh*4+t][ch*2+u] = __builtin_amdgcn_mfma_f32_16x16x32_f16(al[t], bh[u], acc[rh*4+t][ch*2+u], 0, 0, 0);
        }
      }
      __builtin_amdgcn_s_setprio(0);
    };

    auto kstep = [&](const u16* Ac, const u16* Bc, u16* An, u16* Bn,
                     int s, bool more) {
      if (more) {
        if constexpr (INLINE_A) { stageFullB(Bn, s + 1); inlineA(An, s + 1); }
        else { stageFullA(An, s + 1); stageFullB(Bn, s + 1); }
      }
      SCHED0;
      readB(Bc, P ^ 1, Vh, Vl);
      SCHED0;
      MF(ic<P>{}, ic<P>{}, Xh, Xl, Uh, Ul);
      SCHED0;
      readA(Ac, P ^ 1, Yh, Yl);
      SCHED0;
      MF(ic<P>{}, ic<P ^ 1>{}, Xh, Xl, Vh, Vl);
      SCHED0;
      asm volatile("s_waitcnt vmcnt(0) lgkmcnt(0)" ::: "memory");
      __builtin_amdgcn_s_barrier();
      asm volatile("" ::: "memory");
      SCHED0;
      if (more) readA(An, P, Xh, Xl);
      SCHED0;
      MF(ic<P ^ 1>{}, ic<P>{}, Yh, Yl, Uh, Ul);
      SCHED0;
      if (more) readB(Bn, P, Uh, Ul);
      SCHED0;
      MF(ic<P ^ 1>{}, ic<P ^ 1>{}, Yh, Yl, Vh, Vl);
      SCHED0;
    };

    readA(sA0, P, Xh, Xl);
    readB(sB0, P, Uh, Ul);
    #pragma unroll 1
    for (int it = 0; it < 8; ++it) {
      kstep(sA0, sB0, sA1, sB1, it * 2, true);
      kstep(sA1, sB1, sA0, sB0, it * 2 + 1, it < 7);
    }
  };

  if constexpr (INLINE_A) inlineA(sA0, 0); else stageFullA(sA0, 0);
  stageFullB(sB0, 0);
  asm volatile("s_waitcnt vmcnt(0) lgkmcnt(0)" ::: "memory");
  __builtin_amdgcn_s_barrier();
  asm volatile("" ::: "memory");

  // SIMD-mate antiphase: waves map to SIMDs round-robin (wid%4), so mates
  // are (w, w+4). (wid>>2)&1 gives mates OPPOSITE parity -> one reads while
  // the other MFMAs within each section.
  if ((wid >> 2) & 1) kloop(ic<1>{}); else kloop(ic<0>{});

  #undef SCHED0

  float c2v[4];
  #pragma unroll
  for (int j = 0; j < 4; ++j)
    c2v[j] = c2[ntile * 256 + (j >> 1) * 128 + wn * 32 + (j & 1) * 16 + lrow];
  #pragma unroll
  for (int i = 0; i < 8; ++i) {
    #pragma unroll
    for (int jj = 0; jj < 4; ++jj) {
      float v = FLT_MAX; int idx = 0x7fffffff;
      #pragma unroll
      for (int j = 0; j < 4; ++j) {
        const float sc = c2v[j] - 2.0f * acc[i][j][jj];
        const int col = ntile * 256 + (j >> 1) * 128 + wn * 32 + (j & 1) * 16 + lrow;
        if (sc < v || (sc == v && col < idx)) { v = sc; idx = col; }
      }
      #pragma unroll
      for (int m = 1; m < 16; m <<= 1) {
        const float ov = __shfl_xor(v, m);
        const int oi = __shfl_xor(idx, m);
        if (ov < v || (ov == v && oi < idx)) { v = ov; idx = oi; }
      }
      if (lrow == 0) {
        const int row = mtile * 256 + (i >> 2) * 128 + wm * 64 + (i & 3) * 16 + kgrp * 4 + jj;
        part[(size_t)row * 32 + (ntile * 4 + wn)] =
            make_float2(v, __int_as_float(idx));
      }
    }
  }
}

// ---------------- ablation kernel (writes only to scratch) ----------------
// MODE bits: 1=MFMA, 2=DS-READ, 4=STAGE, 8=BARRIERS
template <int MODE>
__global__ __launch_bounds__(512, 2) void vq_abl(
    const u16* __restrict__ Apan, const u16* __restrict__ Bpan,
    float* __restrict__ scratch, int nnt) {
  constexpr bool DO_MFMA  = MODE & 1;
  constexpr bool DO_READ  = MODE & 2;
  constexpr bool DO_STAGE = MODE & 4;
  constexpr bool DO_BAR   = MODE & 8;
  __shared__ u16 sA0[16384], sA1[16384], sB0[16384], sB1[16384];
  const int tid = threadIdx.x;
  const int lane = tid & 63, wid = tid >> 6;
  const int wm = wid >> 2, wn = wid & 3;
  const int nwg = gridDim.x;
  const int bid = blockIdx.x;
  const int swb = (bid & 7) * (nwg >> 3) + (bid >> 3);
  const int mtile = swb / nnt, ntile = swb % nnt;
  const int lrow = lane & 15, kgrp = lane >> 4;
  f32x4 acc[8][4] = {};
  f16x8 Xh[4], Xl[4], Yh[4], Yl[4], Uh[2], Ul[2], Vh[2], Vl[2];
  #pragma unroll
  for (int t = 0; t < 4; ++t) { Xh[t]=f16x8(0); Xl[t]=f16x8(0); Yh[t]=f16x8(0); Yl[t]=f16x8(0); }
  #pragma unroll
  for (int u = 0; u < 2; ++u) { Uh[u]=f16x8(0); Ul[u]=f16x8(0); Vh[u]=f16x8(0); Vl[u]=f16x8(0); }

  auto stageA = [&](u16* dst, int s) {
    const char* g = (const char*)Apan + ((size_t)mtile * 16 + s) * 32768;
    #pragma unroll
    for (int i = 0; i < 4; ++i) {
      const int off = i * 8192 + wid * 1024;
      GL2LDS(g + off + lane * 16, (char*)dst + off);
    }
  };
  auto stageB = [&](u16* dst, int s) {
    const char* g = (const char*)Bpan + ((size_t)ntile * 16 + s) * 32768;
    #pragma unroll
    for (int i = 0; i < 4; ++i) {
      const int off = i * 8192 + wid * 1024;
      GL2LDS(g + off + lane * 16, (char*)dst + off);
    }
  };
  auto readA = [&](const u16* buf, int rh, f16x8* h, f16x8* l) {
    #pragma unroll
    for (int t = 0; t < 4; ++t) {
      const int ar = rh * 128 + wm * 64 + t * 16 + lrow;
      const unsigned swz = ((unsigned)(ar & 7)) << 4;
      const unsigned a0 = (unsigned)(ar * 128 + kgrp * 16);
      h[t] = *reinterpret_cast<const f16x8*>((const char*)buf + (a0 ^ swz));
      l[t] = *reinterpret_cast<const f16x8*>((const char*)buf + ((a0 + 64) ^ swz));
    }
  };
  auto readB = [&](const u16* buf, int ch, f16x8* h, f16x8* l) {
    #pragma unroll
    for (int u = 0; u < 2; ++u) {
      const int br = ch * 128 + wn * 32 + u * 16 + lrow;
      const unsigned swz = ((unsigned)(br & 7)) << 4;
      const unsigned b0 = (unsigned)(br * 128 + kgrp * 16);
      h[u] = *reinterpret_cast<const f16x8*>((const char*)buf + (b0 ^ swz));
      l[u] = *reinterpret_cast<const f16x8*>((const char*)buf + ((b0 + 64) ^ swz));
    }
  };
  auto MFall = [&]() {
    __builtin_amdgcn_s_setprio(1);
    #pragma unroll
    for (int i = 0; i < 8; ++i) {
      const f16x8* ah = (i < 4) ? Xh : Yh;  const f16x8* al = (i < 4) ? Xl : Yl;
      const int t = i & 3;
      #pragma unroll
      for (int j = 0; j < 4; ++j) {
        const f16x8* bh = (j < 2) ? Uh : Vh;  const f16x8* bl = (j < 2) ? Ul : Vl;
        const int u = j & 1;
        acc[i][j] = __builtin_amdgcn_mfma_f32_16x16x32_f16(ah[t], bh[u], acc[i][j], 0, 0, 0);
        acc[i][j] = __builtin_amdgcn_mfma_f32_16x16x32_f16(ah[t], bl[u], acc[i][j], 0, 0, 0);
        acc[i][j] = __builtin_amdgcn_mfma_f32_16x16x32_f16(al[t], bh[u], acc[i][j], 0, 0, 0);
      }
    }
    __builtin_amdgcn_s_setprio(0);
  };
  auto PINALL = [&]() {
    #pragma unroll
    for (int t = 0; t < 4; ++t) { PIN16(Xh[t]); PIN16(Xl[t]); PIN16(Yh[t]); PIN16(Yl[t]); }
    #pragma unroll
    for (int u = 0; u < 2; ++u) { PIN16(Uh[u]); PIN16(Ul[u]); PIN16(Vh[u]); PIN16(Vl[u]); }
  };

  if constexpr (DO_STAGE) {
    stageA(sA0, 0); stageB(sB0, 0);
    asm volatile("s_waitcnt vmcnt(0) lgkmcnt(0)" ::: "memory");
  }
  if constexpr (DO_BAR) __builtin_amdgcn_s_barrier();

  auto kstep = [&](const u16* Ac, const u16* Bc, u16* An, u16* Bn, int s, bool more) {
    if constexpr (DO_STAGE) { if (more) { stageA(An, s + 1); stageB(Bn, s + 1); } }
    if constexpr (DO_READ) {
      readA(Ac, 0, Xh, Xl); readB(Bc, 0, Uh, Ul);
      readA(Ac, 1, Yh, Yl); readB(Bc, 1, Vh, Vl);
      if constexpr (!DO_MFMA) PINALL();
    }
    if constexpr (DO_MFMA) MFall();
    if constexpr (DO_BAR) {
      if constexpr (DO_STAGE) asm volatile("s_waitcnt vmcnt(0)" ::: "memory");
      asm volatile("s_waitcnt lgkmcnt(0)" ::: "memory");
      __builtin_amdgcn_s_barrier();
      asm volatile("" ::: "memory");
    }
  };
  #pragma unroll 1
  for (int it = 0; it < 16; ++it) {
    kstep(sA0, sB0, sA1, sB1, it * 2, true);
    kstep(sA1, sB1, sA0, sB0, it * 2 + 1, it < 15);
  }

  // consume results (prevent DCE) + keep LDS allocated
  float ssum = 0.f;
  #pragma unroll
  for (int i = 0; i < 8; ++i)
    #pragma unroll
    for (int j = 0; j < 4; ++j)
      ssum += acc[i][j][0] + acc[i][j][1] + acc[i][j][2] + acc[i][j][3];
  ssum += (float)Xh[0][0] + (float)Uh[0][0];
  scratch[(size_t)bid * 512 + tid] = ssum;
  if (tid == 0) {
    volatile u16* z0 = sA0; volatile u16* z1 = sA1;
    volatile u16* z2 = sB0; volatile u16* z3 = sB1;
    z0[0] = 1; z1[0] = 1; z2[0] = 1; z3[0] = 1;
  }
}

// Final: reduce 32 partials per row, gather codebook row, write outputs.
__global__ __launch_bounds__(256) void vq_final(
    const float* __restrict__ X, const float* __restrict__ CB,
    const float2* __restrict__ part,
    float* __restrict__ out0, float* __restrict__ out1, float* __restrict__ out2,
    int nsub) {
  const int row = blockIdx.x * 4 + (threadIdx.x >> 6);
  const int l = threadIdx.x & 63;
  float v = FLT_MAX; int idx = 0x7fffffff;
  for (int i = l; i < nsub; i += 64) {
    const float2 p = part[(size_t)row * nsub + i];
    const int pi = __float_as_int(p.y);
    if (p.x < v || (p.x == v && pi < idx)) { v = p.x; idx = pi; }
  }
  #pragma unroll
  for (int m = 1; m < 64; m <<= 1) {
    const float ov = __shfl_xor(v, m);
    const int oi = __shfl_xor(idx, m);
    if (ov < v || (ov == v && oi < idx)) { v = ov; idx = oi; }
  }
  const float4* xr = reinterpret_cast<const float4*>(X + (size_t)row * 512);
  const float4* cr = reinterpret_cast<const float4*>(CB + (size_t)idx * 512);
  float4* q  = reinterpret_cast<float4*>(out0 + (size_t)row * 512);
  float4* ls = reinterpret_cast<float4*>(out1 + (size_t)row * 512);
  #pragma unroll
  for (int p = 0; p < 2; ++p) {
    const int e = l + 64 * p;
    const float4 xv = xr[e], cv = cr[e];
    float4 d4, qv, lv;
    d4.x = cv.x - xv.x; d4.y = cv.y - xv.y; d4.z = cv.z - xv.z; d4.w = cv.w - xv.w;
    qv.x = xv.x + d4.x; qv.y = xv.y + d4.y; qv.z = xv.z + d4.z; qv.w = xv.w + d4.w;
    lv.x = d4.x * d4.x; lv.y = d4.y * d4.y; lv.z = d4.z * d4.z; lv.w = d4.w * d4.w;
    q[e] = qv; ls[e] = lv;
  }
  if (l == 0) out2[row] = (float)idx;
}

extern "C" void kernel_launch(void* const* d_in, const int* in_sizes, int n_in,
                              void* d_out, int out_size, void* d_ws, size_t ws_size,
                              hipStream_t stream) {
  const float* X  = (const float*)d_in[0];   // [M,512] fp32
  const float* CB = (const float*)d_in[1];   // [K,512] fp32
  const int D = 512;
  const int M = in_sizes[0] / D;             // 16384
  const int K = in_sizes[1] / D;             // 2048
  float* out0 = (float*)d_out;
  float* out1 = out0 + (size_t)M * D;
  float* out2 = out1 + (size_t)M * D;
  float* out3 = out2 + M;

  char* ws = (char*)d_ws;
  size_t off = 0;
  u16* Bpan = (u16*)(ws + off); off += (size_t)K * D * 4;
  float* c2 = (float*)(ws + off); off += (size_t)K * 4;
  const int nsub = K / 64;                   // 32
  float2* part = (float2*)(ws + off); off += (size_t)M * nsub * 8;
  u16* Apan = (u16*)(ws + off);
  const size_t need_big = off + (size_t)M * D * 4;
  const bool big = (ws_size >= need_big);

  vq_prep<<<K, 128, 0, stream>>>(CB, Bpan, c2, out3);
  const int nmt = M / 256, nnt = K / 256;
  const int nwg = nmt * nnt;                 // 512
  if (big) {
    vq_prep<<<M, 128, 0, stream>>>(X, Apan, nullptr, nullptr);
    vq_gemm<0><<<nwg, 512, 0, stream>>>(X, Apan, Bpan, c2, part, nnt);
  } else {
    vq_gemm<1><<<nwg, 512, 0, stream>>>(X, nullptr, Bpan, c2, part, nnt);
  }
  vq_final<<<M / 4, 256, 0, stream>>>(X, CB, part, out0, out1, out2, nsub);

  // ---- ablation dispatches (scratch only; stream-ordered after vq_final) --
  if (big) {
    float* scratch = (float*)part;           // part is dead after vq_final
    vq_abl<9><<<nwg, 512, 0, stream>>>(Apan, Bpan, scratch, nnt);   // M1: MFMA+bar
    vq_abl<14><<<nwg, 512, 0, stream>>>(Apan, Bpan, scratch, nnt);  // M2: mem+bar
    vq_abl<3><<<nwg, 512, 0, stream>>>(Apan, Bpan, scratch, nnt);   // M3: MFMA+read free-run
  }
}

// Round 8
// 129.244 us; speedup vs baseline: 3.2449x; 3.2449x over previous
//
#include <hip/hip_runtime.h>
#include <cfloat>

typedef unsigned short u16;
typedef u16   u16x4 __attribute__((ext_vector_type(4)));
typedef float f32x4 __attribute__((ext_vector_type(4)));
typedef _Float16 f16x8 __attribute__((ext_vector_type(8)));

#define GL2LDS(gp, lp) __builtin_amdgcn_global_load_lds(                      \
    (const __attribute__((address_space(1))) void*)(gp),                      \
    (__attribute__((address_space(3))) void*)(lp), 16, 0, 0)

// lexicographic (value, index) less — matches argmin lowest-index tie-break
__device__ __forceinline__ bool vless(float v, int i, float v2, int i2) {
  return v < v2 || (v == v2 && i < i2);
}

// ---------------------------------------------------------------------------
// Pretile a [R,512] fp32 matrix into SINGLE-f16 panels.
// Panel unit: (tile of 256 rows, 64-k slice s) = 256 rows x 128 B = 32 KB.
// Row: [k 0..31 | k 32..63], byte ^= ((r&7)<<4) swizzle (proven 2-way-free).
// Exact LDS image -> linear global_load_lds. Optional c2 + fp32 passthrough.
__global__ __launch_bounds__(128) void vq_prep(
    const float* __restrict__ src, u16* __restrict__ pan,
    float* __restrict__ sq, float* __restrict__ copy_out) {
  __shared__ float red[2];
  const int row_g = blockIdx.x;
  const int t = threadIdx.x;             // 0..127, 4 floats each
  float4 v = reinterpret_cast<const float4*>(src + (size_t)row_g * 512)[t];
  if (copy_out)
    reinterpret_cast<float4*>(copy_out + (size_t)row_g * 512)[t] = v;
  float f[4] = {v.x, v.y, v.z, v.w};
  u16 q[4];
  #pragma unroll
  for (int i = 0; i < 4; ++i)
    q[i] = __builtin_bit_cast(u16, (_Float16)f[i]);   // RNE
  const int d = t * 4;
  const int tile = row_g >> 8, r = row_g & 255;
  const int s = d >> 6, h = (d >> 5) & 1, slot = (d >> 3) & 3, e = d & 7;
  const size_t pbase = ((size_t)tile * 8 + s) * 32768;
  const unsigned boff =
      ((unsigned)(r * 128 + h * 64 + slot * 16 + e * 2)) ^ ((unsigned)(r & 7) << 4);
  u16x4 tq = {q[0], q[1], q[2], q[3]};
  *reinterpret_cast<u16x4*>((char*)pan + pbase + boff) = tq;
  if (sq) {
    float ssum = v.x*v.x + v.y*v.y + v.z*v.z + v.w*v.w;
    #pragma unroll
    for (int m = 1; m < 64; m <<= 1) ssum += __shfl_xor(ssum, m);
    if ((t & 63) == 0) red[t >> 6] = ssum;
    __syncthreads();
    if (t == 0) sq[row_g] = red[0] + red[1];
  }
}

// ---------------------------------------------------------------------------
// Screening GEMM + per-64-col-subtile TOP-2 argmin.
// Tile 256x256, 8 waves (2x4), per-wave 128x64. Single f16 MFMA (16x16x32).
// Period = BK=64 (two k-halves per LDS row); ONE __syncthreads per period;
// reads+MFMA free-scheduled inside the period (M3 ablation: overlap is free).
// score = c2[col] - 2*dot (x2 row-constant, dropped for argmin).
template <int INLINE_A>
__global__ __launch_bounds__(512, 2) void vq_gemm(
    const float* __restrict__ X,
    const u16* __restrict__ Apan, const u16* __restrict__ Bpan,
    const float* __restrict__ c2,
    float4* __restrict__ part, int nnt) {
  __shared__ u16 sA0[16384], sA1[16384], sB0[16384], sB1[16384];  // 4 x 32 KB
  const int tid = threadIdx.x;
  const int lane = tid & 63, wid = tid >> 6;   // 8 waves
  const int wm = wid >> 2, wn = wid & 3;       // 2 x 4
  const int nwg = gridDim.x;
  const int bid = blockIdx.x;
  const int swb = (bid & 7) * (nwg >> 3) + (bid >> 3);  // XCD band swizzle
  const int mtile = swb / nnt, ntile = swb % nnt;
  const int lrow = lane & 15, kgrp = lane >> 4;
  f32x4 acc[8][4] = {};

  auto stage = [&](const u16* pan, int tile, int s2, u16* dst) {
    const char* g = (const char*)pan + ((size_t)tile * 8 + s2) * 32768;
    #pragma unroll
    for (int i = 0; i < 4; ++i) {
      const int off = i * 8192 + wid * 1024;   // wave-uniform LDS base
      GL2LDS(g + off + lane * 16, (char*)dst + off);
    }
  };
  auto inlineA = [&](u16* dst, int s2) {       // fallback: convert X tile
    const float* ga = X + ((size_t)mtile * 256) * 512 + s2 * 64;
    #pragma unroll
    for (int p = 0; p < 8; ++p) {
      const int cch = tid + p * 512;           // 4096 chunks of 4 cols
      const int r = cch >> 4, c0 = (cch & 15) * 4;
      float4 v = *reinterpret_cast<const float4*>(ga + (size_t)r * 512 + c0);
      float f[4] = {v.x, v.y, v.z, v.w};
      u16 q[4];
      #pragma unroll
      for (int i2 = 0; i2 < 4; ++i2)
        q[i2] = __builtin_bit_cast(u16, (_Float16)f[i2]);
      const int h = c0 >> 5, slot = (c0 >> 3) & 3, e = c0 & 7;
      const unsigned boff =
          ((unsigned)(r * 128 + h * 64 + slot * 16 + e * 2)) ^ ((unsigned)(r & 7) << 4);
      u16x4 tq = {q[0], q[1], q[2], q[3]};
      *reinterpret_cast<u16x4*>((char*)dst + boff) = tq;
    }
  };

  auto compute = [&](const u16* Ac, const u16* Bc) {
    #pragma unroll
    for (int h = 0; h < 2; ++h) {
      f16x8 a[8], b[4];
      #pragma unroll
      for (int t2 = 0; t2 < 8; ++t2) {
        const int ar = wm * 128 + t2 * 16 + lrow;
        const unsigned boff =
            ((unsigned)(ar * 128 + h * 64 + kgrp * 16)) ^ ((unsigned)(ar & 7) << 4);
        a[t2] = *reinterpret_cast<const f16x8*>((const char*)Ac + boff);
      }
      #pragma unroll
      for (int u = 0; u < 4; ++u) {
        const int br = wn * 64 + u * 16 + lrow;
        const unsigned boff =
            ((unsigned)(br * 128 + h * 64 + kgrp * 16)) ^ ((unsigned)(br & 7) << 4);
        b[u] = *reinterpret_cast<const f16x8*>((const char*)Bc + boff);
      }
      __builtin_amdgcn_s_setprio(1);
      #pragma unroll
      for (int i = 0; i < 8; ++i)
        #pragma unroll
        for (int j = 0; j < 4; ++j)
          acc[i][j] = __builtin_amdgcn_mfma_f32_16x16x32_f16(a[i], b[j], acc[i][j], 0, 0, 0);
      __builtin_amdgcn_s_setprio(0);
    }
  };

  // prologue: stage period 0
  if constexpr (INLINE_A) inlineA(sA0, 0); else stage(Apan, mtile, 0, sA0);
  stage(Bpan, ntile, 0, sB0);
  __syncthreads();

  #pragma unroll 1
  for (int it = 0; it < 4; ++it) {
    const int p0 = it * 2;
    if (p0 + 1 < 8) {
      if constexpr (INLINE_A) inlineA(sA1, p0 + 1); else stage(Apan, mtile, p0 + 1, sA1);
      stage(Bpan, ntile, p0 + 1, sB1);
    }
    compute(sA0, sB0);
    __syncthreads();
    if (p0 + 2 < 8) {
      if constexpr (INLINE_A) inlineA(sA0, p0 + 2); else stage(Apan, mtile, p0 + 2, sA0);
      stage(Bpan, ntile, p0 + 2, sB0);
    }
    compute(sA1, sB1);
    __syncthreads();
  }

  // ---- epilogue: per-row TOP-2 over this wave's 64 cols (lowest-idx ties)
  float c2v[4];
  #pragma unroll
  for (int j = 0; j < 4; ++j) c2v[j] = c2[ntile * 256 + wn * 64 + j * 16 + lrow];
  #pragma unroll
  for (int i = 0; i < 8; ++i) {
    #pragma unroll
    for (int jj = 0; jj < 4; ++jj) {
      float v1 = FLT_MAX, v2 = FLT_MAX;
      int i1 = 0x7fffffff, i2 = 0x7fffffff;
      #pragma unroll
      for (int j = 0; j < 4; ++j) {
        const float sc = c2v[j] - 2.0f * acc[i][j][jj];
        const int col = ntile * 256 + wn * 64 + j * 16 + lrow;
        if (vless(sc, col, v1, i1)) { v2 = v1; i2 = i1; v1 = sc; i1 = col; }
        else if (vless(sc, col, v2, i2)) { v2 = sc; i2 = col; }
      }
      #pragma unroll
      for (int m = 1; m < 16; m <<= 1) {
        const float ov1 = __shfl_xor(v1, m), ov2 = __shfl_xor(v2, m);
        const int oi1 = __shfl_xor(i1, m), oi2 = __shfl_xor(i2, m);
        if (vless(ov1, oi1, v1, i1)) {
          if (vless(v1, i1, ov2, oi2)) { v2 = v1; i2 = i1; } else { v2 = ov2; i2 = oi2; }
          v1 = ov1; i1 = oi1;
        } else {
          if (vless(ov1, oi1, v2, i2)) { v2 = ov1; i2 = oi1; }
        }
      }
      if (lrow == 0) {
        const int row = mtile * 256 + wm * 128 + i * 16 + kgrp * 4 + jj;
        part[(size_t)row * 32 + (ntile * 4 + wn)] =
            make_float4(v1, __int_as_float(i1), v2, __int_as_float(i2));
      }
    }
  }
}

// ---------------------------------------------------------------------------
// Final: global approx argmin over 64 stored candidates/row; margin-flag;
// exact double-precision refine when >1 candidate within margin; outputs.
__global__ __launch_bounds__(256) void vq_final(
    const float* __restrict__ X, const float* __restrict__ CB,
    const float4* __restrict__ part,
    float* __restrict__ out0, float* __restrict__ out1, float* __restrict__ out2) {
  const int row = blockIdx.x * 4 + (threadIdx.x >> 6);
  const int l = threadIdx.x & 63;
  const float4 p = part[(size_t)row * 32 + (l >> 1)];
  const float v = (l & 1) ? p.z : p.x;
  const int ci = __float_as_int((l & 1) ? p.w : p.y);
  // lexicographic min-reduce over 64 entries
  float rv = v; int ri = ci;
  #pragma unroll
  for (int m = 1; m < 64; m <<= 1) {
    const float ov = __shfl_xor(rv, m);
    const int oi = __shfl_xor(ri, m);
    if (vless(ov, oi, rv, ri)) { rv = ov; ri = oi; }
  }
  int idx;
  unsigned long long mask = __ballot(v <= rv + 0.75f);   // margin M=0.75
  if (__popcll(mask) == 1) {
    idx = ri;                                            // certain winner
  } else {
    float xr[8];
    #pragma unroll
    for (int e = 0; e < 8; ++e) xr[e] = X[(size_t)row * 512 + l + e * 64];
    double bd = 1e300; int bi = 0x7fffffff;
    while (mask) {
      const int sl = __ffsll((long long)mask) - 1;
      mask &= mask - 1;
      const int cidx = __shfl(ci, sl);
      double accd = 0.0;
      #pragma unroll
      for (int e = 0; e < 8; ++e) {
        const double dd = (double)xr[e] - (double)CB[(size_t)cidx * 512 + l + e * 64];
        accd += dd * dd;
      }
      #pragma unroll
      for (int m = 1; m < 64; m <<= 1) accd += __shfl_xor(accd, m);
      if (accd < bd || (accd == bd && cidx < bi)) { bd = accd; bi = cidx; }
    }
    idx = bi;
  }
  const float4* xr4 = reinterpret_cast<const float4*>(X + (size_t)row * 512);
  const float4* cr4 = reinterpret_cast<const float4*>(CB + (size_t)idx * 512);
  float4* q  = reinterpret_cast<float4*>(out0 + (size_t)row * 512);
  float4* ls = reinterpret_cast<float4*>(out1 + (size_t)row * 512);
  #pragma unroll
  for (int pp = 0; pp < 2; ++pp) {
    const int e = l + 64 * pp;
    const float4 xv = xr4[e], cv = cr4[e];
    float4 d4, qv, lv;
    d4.x = cv.x - xv.x; d4.y = cv.y - xv.y; d4.z = cv.z - xv.z; d4.w = cv.w - xv.w;
    qv.x = xv.x + d4.x; qv.y = xv.y + d4.y; qv.z = xv.z + d4.z; qv.w = xv.w + d4.w;
    lv.x = d4.x * d4.x; lv.y = d4.y * d4.y; lv.z = d4.z * d4.z; lv.w = d4.w * d4.w;
    q[e] = qv; ls[e] = lv;
  }
  if (l == 0) out2[row] = (float)idx;
}

extern "C" void kernel_launch(void* const* d_in, const int* in_sizes, int n_in,
                              void* d_out, int out_size, void* d_ws, size_t ws_size,
                              hipStream_t stream) {
  const float* X  = (const float*)d_in[0];   // [M,512] fp32
  const float* CB = (const float*)d_in[1];   // [K,512] fp32
  const int D = 512;
  const int M = in_sizes[0] / D;             // 16384
  const int K = in_sizes[1] / D;             // 2048
  float* out0 = (float*)d_out;               // quantized_ste [M,512]
  float* out1 = out0 + (size_t)M * D;        // loss          [M,512]
  float* out2 = out1 + (size_t)M * D;        // nn_idx (as f32) [M]
  float* out3 = out2 + M;                    // codebook copy [K,512]

  char* ws = (char*)d_ws;
  size_t off = 0;
  u16* Bpan = (u16*)(ws + off); off += (size_t)K * D * 2;     // f16 panels
  float* c2 = (float*)(ws + off); off += (size_t)K * 4;
  float4* part = (float4*)(ws + off); off += (size_t)M * 32 * 16;
  u16* Apan = (u16*)(ws + off);
  const size_t need_big = off + (size_t)M * D * 2;
  const bool big = (ws_size >= need_big);

  vq_prep<<<K, 128, 0, stream>>>(CB, Bpan, c2, out3);
  const int nmt = M / 256, nnt = K / 256;
  const int nwg = nmt * nnt;                                  // 512
  if (big) {
    vq_prep<<<M, 128, 0, stream>>>(X, Apan, nullptr, nullptr);
    vq_gemm<0><<<nwg, 512, 0, stream>>>(X, Apan, Bpan, c2, part, nnt);
  } else {
    vq_gemm<1><<<nwg, 512, 0, stream>>>(X, nullptr, Bpan, c2, part, nnt);
  }
  vq_final<<<M / 4, 256, 0, stream>>>(X, CB, part, out0, out1, out2);
}

// Round 9
// 88.643 us; speedup vs baseline: 4.7311x; 1.4580x over previous
//
#include <hip/hip_runtime.h>
#include <cfloat>

typedef unsigned short u16;
typedef unsigned int u32;
typedef u16   u16x4 __attribute__((ext_vector_type(4)));
typedef float f32x4 __attribute__((ext_vector_type(4)));
typedef _Float16 f16x8 __attribute__((ext_vector_type(8)));

#define GL2LDS(gp, lp) __builtin_amdgcn_global_load_lds(                      \
    (const __attribute__((address_space(1))) void*)(gp),                      \
    (__attribute__((address_space(3))) void*)(lp), 16, 0, 0)

// lexicographic (value, index) less — matches argmin lowest-index tie-break
__device__ __forceinline__ bool vless(float v, int i, float v2, int i2) {
  return v < v2 || (v == v2 && i < i2);
}

// monotonic float->uint map (order-preserving for all finite floats)
__device__ __forceinline__ u32 fmono(float f) {
  u32 u = __float_as_uint(f);
  return u ^ (0x80000000u | (u32)((int)u >> 31));
}
__device__ __forceinline__ float fmono_inv(u32 m) {
  u32 u = (m & 0x80000000u) ? (m ^ 0x80000000u) : ~m;
  return __uint_as_float(u);
}

// ---------------------------------------------------------------------------
// Pretile a [R,512] fp32 matrix into SINGLE-f16 panels.
// Panel unit: (tile of 128 rows, 64-k slice s) = 128 rows x 128 B = 16 KB.
// Row: [k 0..31 | k 32..63], byte ^= ((r&7)<<4) swizzle (proven 2-way-free).
// Exact LDS image -> linear global_load_lds. Optional c2 + fp32 passthrough.
__global__ __launch_bounds__(128) void vq_prep(
    const float* __restrict__ src, u16* __restrict__ pan,
    float* __restrict__ sq, float* __restrict__ copy_out) {
  __shared__ float red[2];
  const int row_g = blockIdx.x;
  const int t = threadIdx.x;             // 0..127, 4 floats each
  float4 v = reinterpret_cast<const float4*>(src + (size_t)row_g * 512)[t];
  if (copy_out)
    reinterpret_cast<float4*>(copy_out + (size_t)row_g * 512)[t] = v;
  float f[4] = {v.x, v.y, v.z, v.w};
  u16 q[4];
  #pragma unroll
  for (int i = 0; i < 4; ++i)
    q[i] = __builtin_bit_cast(u16, (_Float16)f[i]);   // RNE
  const int d = t * 4;
  const int tile = row_g >> 7, r = row_g & 127;
  const int s = d >> 6, h = (d >> 5) & 1, slot = (d >> 3) & 3, e = d & 7;
  const size_t pbase = ((size_t)tile * 8 + s) * 16384;
  const unsigned boff =
      ((unsigned)(r * 128 + h * 64 + slot * 16 + e * 2)) ^ ((unsigned)(r & 7) << 4);
  u16x4 tq = {q[0], q[1], q[2], q[3]};
  *reinterpret_cast<u16x4*>((char*)pan + pbase + boff) = tq;
  if (sq) {
    float ssum = v.x*v.x + v.y*v.y + v.z*v.z + v.w*v.w;
    #pragma unroll
    for (int m = 1; m < 64; m <<= 1) ssum += __shfl_xor(ssum, m);
    if ((t & 63) == 0) red[t >> 6] = ssum;
    __syncthreads();
    if (t == 0) sq[row_g] = red[0] + red[1];
  }
}

// ---------------------------------------------------------------------------
// Screening GEMM + per-64-col-subtile TOP-2 (packed-key) argmin.
// OCCUPANCY CONFIG: tile 128x128, 4 waves (2x2), per-wave 64x64, LDS 32 KB
// single-buffered, __launch_bounds__(256,4) -> VGPR<=128 -> 4 blocks/CU,
// 16 waves/CU. Inter-block async hides staging latency + barrier drains.
// score = c2[col] - 2*dot (x2 row-constant, dropped for argmin).
template <int INLINE_A>
__global__ __launch_bounds__(256, 4) void vq_gemm(
    const float* __restrict__ X,
    const u16* __restrict__ Apan, const u16* __restrict__ Bpan,
    const float* __restrict__ c2,
    float4* __restrict__ part, int nnt) {
  __shared__ u16 sA[8192], sB[8192];           // 16 KB + 16 KB
  const int tid = threadIdx.x;
  const int lane = tid & 63, wid = tid >> 6;   // 4 waves
  const int wm = wid >> 1, wn = wid & 1;       // 2 x 2
  const int nwg = gridDim.x;
  const int bid = blockIdx.x;
  const int swb = (bid & 7) * (nwg >> 3) + (bid >> 3);  // XCD band swizzle
  const int mtile = swb / nnt, ntile = swb % nnt;
  const int lrow = lane & 15, kgrp = lane >> 4;
  f32x4 acc[4][4] = {};

  auto stage = [&](const u16* pan, int tile, int s2, u16* dst) {
    const char* g = (const char*)pan + ((size_t)tile * 8 + s2) * 16384;
    #pragma unroll
    for (int i = 0; i < 4; ++i) {
      const int off = (wid * 4 + i) * 1024;    // wave-uniform LDS base
      GL2LDS(g + off + lane * 16, (char*)dst + off);
    }
  };
  auto inlineA = [&](u16* dst, int s2) {       // fallback: convert X tile
    const float* ga = X + ((size_t)mtile * 128) * 512 + s2 * 64;
    #pragma unroll
    for (int p = 0; p < 8; ++p) {
      const int cch = tid + p * 256;           // 2048 chunks of 4 cols
      const int r = cch >> 4, c0 = (cch & 15) * 4;
      float4 v = *reinterpret_cast<const float4*>(ga + (size_t)r * 512 + c0);
      float f[4] = {v.x, v.y, v.z, v.w};
      u16 q[4];
      #pragma unroll
      for (int i2 = 0; i2 < 4; ++i2)
        q[i2] = __builtin_bit_cast(u16, (_Float16)f[i2]);
      const int h = c0 >> 5, slot = (c0 >> 3) & 3, e = c0 & 7;
      const unsigned boff =
          ((unsigned)(r * 128 + h * 64 + slot * 16 + e * 2)) ^ ((unsigned)(r & 7) << 4);
      u16x4 tq = {q[0], q[1], q[2], q[3]};
      *reinterpret_cast<u16x4*>((char*)dst + boff) = tq;
    }
  };

  #pragma unroll 1
  for (int s = 0; s < 8; ++s) {
    __syncthreads();                           // readers of prev period done
    if constexpr (INLINE_A) inlineA(sA, s); else stage(Apan, mtile, s, sA);
    stage(Bpan, ntile, s, sB);
    __syncthreads();                           // staged data visible
    #pragma unroll
    for (int h = 0; h < 2; ++h) {
      f16x8 a[4], b[4];
      #pragma unroll
      for (int t2 = 0; t2 < 4; ++t2) {
        const int ar = wm * 64 + t2 * 16 + lrow;
        const unsigned boff =
            ((unsigned)(ar * 128 + h * 64 + kgrp * 16)) ^ ((unsigned)(ar & 7) << 4);
        a[t2] = *reinterpret_cast<const f16x8*>((const char*)sA + boff);
      }
      #pragma unroll
      for (int u = 0; u < 4; ++u) {
        const int br = wn * 64 + u * 16 + lrow;
        const unsigned boff =
            ((unsigned)(br * 128 + h * 64 + kgrp * 16)) ^ ((unsigned)(br & 7) << 4);
        b[u] = *reinterpret_cast<const f16x8*>((const char*)sB + boff);
      }
      __builtin_amdgcn_s_setprio(1);
      #pragma unroll
      for (int i = 0; i < 4; ++i)
        #pragma unroll
        for (int j = 0; j < 4; ++j)
          acc[i][j] = __builtin_amdgcn_mfma_f32_16x16x32_f16(a[i], b[j], acc[i][j], 0, 0, 0);
      __builtin_amdgcn_s_setprio(0);
    }
  }

  // ---- epilogue: per-row TOP-2 over this wave's 64 cols via packed keys.
  // key = (monotonic(score) & ~0x7FF) | col  -> uint min == (quantized score,
  // col) lexicographic. Quantization <=0.25 absorbed by final margin (1.0).
  float c2v[4];
  #pragma unroll
  for (int j = 0; j < 4; ++j) c2v[j] = c2[ntile * 128 + wn * 64 + j * 16 + lrow];
  #pragma unroll
  for (int i = 0; i < 4; ++i) {
    #pragma unroll
    for (int jj = 0; jj < 4; ++jj) {
      u32 k1 = 0xFFFFFFFFu, k2 = 0xFFFFFFFFu;
      #pragma unroll
      for (int j = 0; j < 4; ++j) {
        const float sc = c2v[j] - 2.0f * acc[i][j][jj];
        const u32 col = (u32)(ntile * 128 + wn * 64 + j * 16 + lrow);
        const u32 k = (fmono(sc) & 0xFFFFF800u) | col;
        if (k < k1) { k2 = k1; k1 = k; } else if (k < k2) { k2 = k; }
      }
      #pragma unroll
      for (int m = 1; m < 16; m <<= 1) {
        const u32 ok1 = (u32)__shfl_xor((int)k1, m);
        const u32 ok2 = (u32)__shfl_xor((int)k2, m);
        const u32 lo = min(k1, ok1), hi = max(k1, ok1);
        k1 = lo;
        k2 = min(hi, min(k2, ok2));
      }
      if (lrow == 0) {
        const int row = mtile * 128 + wm * 64 + i * 16 + kgrp * 4 + jj;
        part[(size_t)row * 32 + (ntile * 2 + wn)] =
            make_float4(fmono_inv(k1 & 0xFFFFF800u), __int_as_float((int)(k1 & 0x7FFu)),
                        fmono_inv(k2 & 0xFFFFF800u), __int_as_float((int)(k2 & 0x7FFu)));
      }
    }
  }
}

// ---------------------------------------------------------------------------
// Final: global approx argmin over 64 stored candidates/row; margin-flag;
// exact double-precision refine when >1 candidate within margin; outputs.
__global__ __launch_bounds__(256) void vq_final(
    const float* __restrict__ X, const float* __restrict__ CB,
    const float4* __restrict__ part,
    float* __restrict__ out0, float* __restrict__ out1, float* __restrict__ out2) {
  const int row = blockIdx.x * 4 + (threadIdx.x >> 6);
  const int l = threadIdx.x & 63;
  const float4 p = part[(size_t)row * 32 + (l >> 1)];
  const float v = (l & 1) ? p.z : p.x;
  const int ci = __float_as_int((l & 1) ? p.w : p.y);
  // lexicographic min-reduce over 64 entries
  float rv = v; int ri = ci;
  #pragma unroll
  for (int m = 1; m < 64; m <<= 1) {
    const float ov = __shfl_xor(rv, m);
    const int oi = __shfl_xor(ri, m);
    if (vless(ov, oi, rv, ri)) { rv = ov; ri = oi; }
  }
  int idx;
  unsigned long long mask = __ballot(v <= rv + 1.0f);   // margin (f16 err + key quant)
  if (__popcll(mask) == 1) {
    idx = ri;                                            // certain winner
  } else {
    float xr[8];
    #pragma unroll
    for (int e = 0; e < 8; ++e) xr[e] = X[(size_t)row * 512 + l + e * 64];
    double bd = 1e300; int bi = 0x7fffffff;
    while (mask) {
      const int sl = __ffsll((long long)mask) - 1;
      mask &= mask - 1;
      const int cidx = __shfl(ci, sl);
      double accd = 0.0;
      #pragma unroll
      for (int e = 0; e < 8; ++e) {
        const double dd = (double)xr[e] - (double)CB[(size_t)cidx * 512 + l + e * 64];
        accd += dd * dd;
      }
      #pragma unroll
      for (int m = 1; m < 64; m <<= 1) accd += __shfl_xor(accd, m);
      if (accd < bd || (accd == bd && cidx < bi)) { bd = accd; bi = cidx; }
    }
    idx = bi;
  }
  const float4* xr4 = reinterpret_cast<const float4*>(X + (size_t)row * 512);
  const float4* cr4 = reinterpret_cast<const float4*>(CB + (size_t)idx * 512);
  float4* q  = reinterpret_cast<float4*>(out0 + (size_t)row * 512);
  float4* ls = reinterpret_cast<float4*>(out1 + (size_t)row * 512);
  #pragma unroll
  for (int pp = 0; pp < 2; ++pp) {
    const int e = l + 64 * pp;
    const float4 xv = xr4[e], cv = cr4[e];
    float4 d4, qv, lv;
    d4.x = cv.x - xv.x; d4.y = cv.y - xv.y; d4.z = cv.z - xv.z; d4.w = cv.w - xv.w;
    qv.x = xv.x + d4.x; qv.y = xv.y + d4.y; qv.z = xv.z + d4.z; qv.w = xv.w + d4.w;
    lv.x = d4.x * d4.x; lv.y = d4.y * d4.y; lv.z = d4.z * d4.z; lv.w = d4.w * d4.w;
    q[e] = qv; ls[e] = lv;
  }
  if (l == 0) out2[row] = (float)idx;
}

extern "C" void kernel_launch(void* const* d_in, const int* in_sizes, int n_in,
                              void* d_out, int out_size, void* d_ws, size_t ws_size,
                              hipStream_t stream) {
  const float* X  = (const float*)d_in[0];   // [M,512] fp32
  const float* CB = (const float*)d_in[1];   // [K,512] fp32
  const int D = 512;
  const int M = in_sizes[0] / D;             // 16384
  const int K = in_sizes[1] / D;             // 2048
  float* out0 = (float*)d_out;               // quantized_ste [M,512]
  float* out1 = out0 + (size_t)M * D;        // loss          [M,512]
  float* out2 = out1 + (size_t)M * D;        // nn_idx (as f32) [M]
  float* out3 = out2 + M;                    // codebook copy [K,512]

  char* ws = (char*)d_ws;
  size_t off = 0;
  u16* Bpan = (u16*)(ws + off); off += (size_t)K * D * 2;     // f16 panels
  float* c2 = (float*)(ws + off); off += (size_t)K * 4;
  float4* part = (float4*)(ws + off); off += (size_t)M * 32 * 16;
  u16* Apan = (u16*)(ws + off);
  const size_t need_big = off + (size_t)M * D * 2;
  const bool big = (ws_size >= need_big);

  vq_prep<<<K, 128, 0, stream>>>(CB, Bpan, c2, out3);
  const int nmt = M / 128, nnt = K / 128;                     // 128 x 16
  const int nwg = nmt * nnt;                                  // 2048
  if (big) {
    vq_prep<<<M, 128, 0, stream>>>(X, Apan, nullptr, nullptr);
    vq_gemm<0><<<nwg, 256, 0, stream>>>(X, Apan, Bpan, c2, part, nnt);
  } else {
    vq_gemm<1><<<nwg, 256, 0, stream>>>(X, nullptr, Bpan, c2, part, nnt);
  }
  vq_final<<<M / 4, 256, 0, stream>>>(X, CB, part, out0, out1, out2);
}